// Round 1
// baseline (1571.950 us; speedup 1.0000x reference)
//
#include <hip/hip_runtime.h>
#include <hip/hip_bf16.h>
#include <math.h>

// Problem constants
#define B 8
#define M 1024
#define D 768
#define NEXP 64
#define P 16
#define H 1536
#define S (NEXP*P)      // 1024 slots
#define EPS_NORM 1e-6f
#define EPS_LN   1e-5f

// GEMM tiling
#define TILE 64
#define BKK  16
#define LDP  68   // padded LDS leading dim (68*4=272 B, 16B-aligned rows, 2-way bank alias only)

__device__ __forceinline__ float gelu_exact(float x) {
    return 0.5f * x * (1.0f + erff(x * 0.70710678118654752440f));
}

__device__ __forceinline__ void tile_compute(const float* As, const float* Bs,
                                             int tx, int ty, float acc[4][4]) {
#pragma unroll
    for (int kk = 0; kk < BKK; ++kk) {
        const float4 a4 = *(const float4*)(As + kk*LDP + ty*4);
        const float4 b4 = *(const float4*)(Bs + kk*LDP + tx*4);
        float a[4] = {a4.x, a4.y, a4.z, a4.w};
        float b[4] = {b4.x, b4.y, b4.z, b4.w};
#pragma unroll
        for (int i = 0; i < 4; ++i)
#pragma unroll
            for (int j = 0; j < 4; ++j)
                acc[i][j] = fmaf(a[i], b[j], acc[i][j]);
    }
}

// ---------------------------------------------------------------------------
// 0) phi_n[n,p,d] = phi[n,p,d] * rsqrt(sum_n phi^2 + eps)
__global__ __launch_bounds__(256) void phi_norm_kernel(const float* __restrict__ phi,
                                                       float* __restrict__ phin) {
    int pos = blockIdx.x * 256 + threadIdx.x;   // 0..P*D-1 (12288)
    float ss = 0.f;
#pragma unroll 4
    for (int nn = 0; nn < NEXP; ++nn) {
        float v = phi[nn * (P*D) + pos];
        ss += v * v;
    }
    float r = rsqrtf(ss + EPS_NORM);
#pragma unroll 4
    for (int nn = 0; nn < NEXP; ++nn)
        phin[nn * (P*D) + pos] = phi[nn * (P*D) + pos] * r;
}

// ---------------------------------------------------------------------------
// 1) NT GEMM: C[M,N] = A(M,K) * B(N,K)^T, row-major; lda=ldb=K, ldc=N
__global__ __launch_bounds__(256) void gemm_nt_kernel(const float* __restrict__ A,
                                                      const float* __restrict__ Bm,
                                                      float* __restrict__ C,
                                                      int Mm, int Nn, int K) {
    __shared__ float As[BKK*LDP];
    __shared__ float Bs[BKK*LDP];
    int t = threadIdx.x;
    int tx = t & 15, ty = t >> 4;
    int row0 = blockIdx.y * TILE, col0 = blockIdx.x * TILE;
    int lr = t >> 2;            // 0..63
    int lk = (t & 3) << 2;      // 0,4,8,12
    const float* Ap = A  + (size_t)(row0 + lr) * K + lk;
    const float* Bp = Bm + (size_t)(col0 + lr) * K + lk;
    float acc[4][4] = {};
    for (int k0 = 0; k0 < K; k0 += BKK) {
        float4 av = *(const float4*)(Ap + k0);
        float4 bv = *(const float4*)(Bp + k0);
        __syncthreads();
        As[(lk+0)*LDP+lr]=av.x; As[(lk+1)*LDP+lr]=av.y; As[(lk+2)*LDP+lr]=av.z; As[(lk+3)*LDP+lr]=av.w;
        Bs[(lk+0)*LDP+lr]=bv.x; Bs[(lk+1)*LDP+lr]=bv.y; Bs[(lk+2)*LDP+lr]=bv.z; Bs[(lk+3)*LDP+lr]=bv.w;
        __syncthreads();
        tile_compute(As, Bs, tx, ty, acc);
    }
#pragma unroll
    for (int i = 0; i < 4; ++i) {
        float4 o = make_float4(acc[i][0], acc[i][1], acc[i][2], acc[i][3]);
        *(float4*)(C + (size_t)(row0 + ty*4 + i) * Nn + col0 + tx*4) = o;
    }
}

// ---------------------------------------------------------------------------
// 2) row softmax over 1024 cols; one block per row
__global__ __launch_bounds__(256) void softmax_row_kernel(const float* __restrict__ in,
                                                          float* __restrict__ out) {
    __shared__ float red[4], red2[4];
    int row = blockIdx.x;
    int t = threadIdx.x;
    const float* rp = in + (size_t)row * S;
    float4 v = *(const float4*)(rp + t*4);
    float mx = fmaxf(fmaxf(v.x, v.y), fmaxf(v.z, v.w));
#pragma unroll
    for (int o = 1; o < 64; o <<= 1) mx = fmaxf(mx, __shfl_xor(mx, o));
    if ((t & 63) == 0) red[t >> 6] = mx;
    __syncthreads();
    mx = fmaxf(fmaxf(red[0], red[1]), fmaxf(red[2], red[3]));
    float4 e;
    e.x = expf(v.x - mx); e.y = expf(v.y - mx); e.z = expf(v.z - mx); e.w = expf(v.w - mx);
    float sum = e.x + e.y + e.z + e.w;
#pragma unroll
    for (int o = 1; o < 64; o <<= 1) sum += __shfl_xor(sum, o);
    if ((t & 63) == 0) red2[t >> 6] = sum;
    __syncthreads();
    sum = red2[0] + red2[1] + red2[2] + red2[3];
    float inv = 1.f / sum;
    e.x *= inv; e.y *= inv; e.z *= inv; e.w *= inv;
    *(float4*)(out + (size_t)row * S + t*4) = e;
}

// ---------------------------------------------------------------------------
// 3) column softmax over m (axis=1), split in 3 phases.
// partial: 8 chunks of 128 rows each, online (max, sumexp) per (chunk, col)
__global__ __launch_bounds__(256) void colsm_partial_kernel(const float* __restrict__ logits,
                                                            float* __restrict__ pm,
                                                            float* __restrict__ pl) {
    int gid = blockIdx.x * 256 + threadIdx.x;    // 0..65535
    int c   = gid >> 13;                         // 0..7
    int col = gid & 8191;                        // b*S + s
    int b = col >> 10, s = col & (S - 1);
    const float* base = logits + ((size_t)b << 20) + ((size_t)(c * 128) << 10) + s;
    float mx = -INFINITY, l = 0.f;
    for (int m = 0; m < 128; ++m) {
        float v = base[(size_t)m << 10];
        float nm = fmaxf(mx, v);
        l = l * expf(mx - nm) + expf(v - nm);
        mx = nm;
    }
    pm[gid] = mx;
    pl[gid] = l;
}

__global__ __launch_bounds__(256) void colsm_combine_kernel(const float* __restrict__ pm,
                                                            const float* __restrict__ pl,
                                                            float* __restrict__ fm,
                                                            float* __restrict__ fl) {
    int col = blockIdx.x * 256 + threadIdx.x;    // 0..8191
    float mx = -INFINITY;
#pragma unroll
    for (int c = 0; c < 8; ++c) mx = fmaxf(mx, pm[c * 8192 + col]);
    float l = 0.f;
#pragma unroll
    for (int c = 0; c < 8; ++c) l += pl[c * 8192 + col] * expf(pm[c * 8192 + col] - mx);
    fm[col] = mx;
    fl[col] = 1.f / l;
}

__global__ __launch_bounds__(256) void colsm_norm_kernel(float* __restrict__ logits,
                                                         const float* __restrict__ fm,
                                                         const float* __restrict__ fl) {
    int i = blockIdx.x * 256 + threadIdx.x;      // element/4 index
    size_t off = (size_t)i * 4;
    int b = (int)(off >> 20);
    int s = (int)(off & (S - 1));
    int col = (b << 10) + s;
    float4 v   = *(float4*)(logits + off);
    float4 fmv = *(const float4*)(fm + col);
    float4 flv = *(const float4*)(fl + col);
    v.x = expf(v.x - fmv.x) * flv.x;
    v.y = expf(v.y - fmv.y) * flv.y;
    v.z = expf(v.z - fmv.z) * flv.z;
    v.w = expf(v.w - fmv.w) * flv.w;
    *(float4*)(logits + off) = v;
}

// ---------------------------------------------------------------------------
// 4) TN GEMM batched over b: C[i,j] = sum_k A[k*lda+i] * B[k*ldb+j]
//    (Xs_b[s,d] = sum_m D_b[m,s] * x_b[m,d])
__global__ __launch_bounds__(256) void gemm_tn_batched_kernel(const float* __restrict__ A,
                                                              const float* __restrict__ Bm,
                                                              float* __restrict__ C,
                                                              int Mm, int Nn, int K,
                                                              int lda, int ldb, int ldc,
                                                              size_t aStride, size_t bStride, size_t cStride) {
    __shared__ float As[BKK*LDP];
    __shared__ float Bs[BKK*LDP];
    int bz = blockIdx.z;
    const float* Ab = A  + bz * aStride;
    const float* Bb = Bm + bz * bStride;
    float*       Cb = C  + bz * cStride;
    int t = threadIdx.x;
    int tx = t & 15, ty = t >> 4;
    int row0 = blockIdx.y * TILE, col0 = blockIdx.x * TILE;
    int lk16 = t >> 4;          // k row 0..15
    int li   = (t & 15) << 2;   // 0,4,..,60
    float acc[4][4] = {};
    for (int k0 = 0; k0 < K; k0 += BKK) {
        float4 av = *(const float4*)(Ab + (size_t)(k0 + lk16) * lda + row0 + li);
        float4 bv = *(const float4*)(Bb + (size_t)(k0 + lk16) * ldb + col0 + li);
        __syncthreads();
        *(float4*)(As + lk16*LDP + li) = av;
        *(float4*)(Bs + lk16*LDP + li) = bv;
        __syncthreads();
        tile_compute(As, Bs, tx, ty, acc);
    }
#pragma unroll
    for (int i = 0; i < 4; ++i) {
        float4 o = make_float4(acc[i][0], acc[i][1], acc[i][2], acc[i][3]);
        *(float4*)(Cb + (size_t)(row0 + ty*4 + i) * ldc + col0 + tx*4) = o;
    }
}

// ---------------------------------------------------------------------------
// 5) LayerNorm in-place over rows of Xs, per-expert affine
__global__ __launch_bounds__(256) void layernorm_kernel(float* __restrict__ Xs,
                                                        const float* __restrict__ g,
                                                        const float* __restrict__ bt) {
    __shared__ float rs[4], rq[4];
    int row = blockIdx.x;                  // b*1024 + n*16 + p
    int n = (row >> 4) & (NEXP - 1);
    float* rp = Xs + (size_t)row * D;
    int t = threadIdx.x;
    float x0 = rp[t], x1 = rp[t + 256], x2 = rp[t + 512];
    float s  = x0 + x1 + x2;
    float sq = x0*x0 + x1*x1 + x2*x2;
#pragma unroll
    for (int o = 1; o < 64; o <<= 1) { s += __shfl_xor(s, o); sq += __shfl_xor(sq, o); }
    if ((t & 63) == 0) { rs[t >> 6] = s; rq[t >> 6] = sq; }
    __syncthreads();
    s  = rs[0] + rs[1] + rs[2] + rs[3];
    sq = rq[0] + rq[1] + rq[2] + rq[3];
    float mu  = s * (1.f / D);
    float var = sq * (1.f / D) - mu * mu;
    float inv = rsqrtf(var + EPS_LN);
    const float* gn = g  + n * D;
    const float* bn = bt + n * D;
    rp[t]       = (x0 - mu) * inv * gn[t]       + bn[t];
    rp[t + 256] = (x1 - mu) * inv * gn[t + 256] + bn[t + 256];
    rp[t + 512] = (x2 - mu) * inv * gn[t + 512] + bn[t + 512];
}

// ---------------------------------------------------------------------------
// 6) Expert MLP stage 1: h1[n, r, :] = gelu( hdn_row(n,r) @ w1[n] + b1[n] )
//    r in [0,128): b = r>>4, p = r&15; hdn row at Xs[((b*64+n)*16+p)*768]
__global__ __launch_bounds__(256) void expert_mlp1_kernel(const float* __restrict__ Xs,
                                                          const float* __restrict__ w1,
                                                          const float* __restrict__ b1,
                                                          float* __restrict__ h1) {
    __shared__ float As[BKK*LDP];
    __shared__ float Bs[BKK*LDP];
    int n = blockIdx.z;
    int t = threadIdx.x;
    int tx = t & 15, ty = t >> 4;
    int row0 = blockIdx.y * TILE, col0 = blockIdx.x * TILE;
    int lr = t >> 2, lk = (t & 3) << 2;
    int r = row0 + lr;
    const float* Ap  = Xs + ((size_t)((r >> 4) * NEXP + n) * P + (r & 15)) * D + lk;
    const float* w1n = w1 + (size_t)n * D * H;
    int lk16 = t >> 4;
    int li   = (t & 15) << 2;
    float acc[4][4] = {};
    for (int k0 = 0; k0 < D; k0 += BKK) {
        float4 av = *(const float4*)(Ap + k0);
        float4 bv = *(const float4*)(w1n + (size_t)(k0 + lk16) * H + col0 + li);
        __syncthreads();
        As[(lk+0)*LDP+lr]=av.x; As[(lk+1)*LDP+lr]=av.y; As[(lk+2)*LDP+lr]=av.z; As[(lk+3)*LDP+lr]=av.w;
        *(float4*)(Bs + lk16*LDP + li) = bv;
        __syncthreads();
        tile_compute(As, Bs, tx, ty, acc);
    }
#pragma unroll
    for (int i = 0; i < 4; ++i) {
        int rr = row0 + ty*4 + i;
        int col = col0 + tx*4;
        float4 o;
        o.x = gelu_exact(acc[i][0] + b1[n*H + col + 0]);
        o.y = gelu_exact(acc[i][1] + b1[n*H + col + 1]);
        o.z = gelu_exact(acc[i][2] + b1[n*H + col + 2]);
        o.w = gelu_exact(acc[i][3] + b1[n*H + col + 3]);
        *(float4*)(h1 + ((size_t)n * 128 + rr) * H + col) = o;
    }
}

// ---------------------------------------------------------------------------
// 7) Expert MLP stage 2: Ys[b, n*16+p, :] = h1[n, r, :] @ w2[n] + b2[n]
__global__ __launch_bounds__(256) void expert_mlp2_kernel(const float* __restrict__ h1,
                                                          const float* __restrict__ w2,
                                                          const float* __restrict__ b2,
                                                          float* __restrict__ Ys) {
    __shared__ float As[BKK*LDP];
    __shared__ float Bs[BKK*LDP];
    int n = blockIdx.z;
    int t = threadIdx.x;
    int tx = t & 15, ty = t >> 4;
    int row0 = blockIdx.y * TILE, col0 = blockIdx.x * TILE;
    int lr = t >> 2, lk = (t & 3) << 2;
    const float* Ap  = h1 + ((size_t)n * 128 + row0 + lr) * H + lk;
    const float* w2n = w2 + (size_t)n * H * D;
    int lk16 = t >> 4;
    int li   = (t & 15) << 2;
    float acc[4][4] = {};
    for (int k0 = 0; k0 < H; k0 += BKK) {
        float4 av = *(const float4*)(Ap + k0);
        float4 bv = *(const float4*)(w2n + (size_t)(k0 + lk16) * D + col0 + li);
        __syncthreads();
        As[(lk+0)*LDP+lr]=av.x; As[(lk+1)*LDP+lr]=av.y; As[(lk+2)*LDP+lr]=av.z; As[(lk+3)*LDP+lr]=av.w;
        *(float4*)(Bs + lk16*LDP + li) = bv;
        __syncthreads();
        tile_compute(As, Bs, tx, ty, acc);
    }
#pragma unroll
    for (int i = 0; i < 4; ++i) {
        int rr = row0 + ty*4 + i;       // 0..127
        int bb = rr >> 4, pp = rr & 15;
        int col = col0 + tx*4;
        float4 o;
        o.x = acc[i][0] + b2[n*D + col + 0];
        o.y = acc[i][1] + b2[n*D + col + 1];
        o.z = acc[i][2] + b2[n*D + col + 2];
        o.w = acc[i][3] + b2[n*D + col + 3];
        *(float4*)(Ys + ((size_t)bb * S + n * P + pp) * D + col) = o;
    }
}

// ---------------------------------------------------------------------------
// 8) NN GEMM batched over b: Y_b[m,d] = sum_s C_b[m,s] * Ys_b[s,d]
__global__ __launch_bounds__(256) void gemm_nn_batched_kernel(const float* __restrict__ A,
                                                              const float* __restrict__ Bm,
                                                              float* __restrict__ C,
                                                              int Mm, int Nn, int K,
                                                              int lda, int ldb, int ldc,
                                                              size_t aStride, size_t bStride, size_t cStride) {
    __shared__ float As[BKK*LDP];
    __shared__ float Bs[BKK*LDP];
    int bz = blockIdx.z;
    const float* Ab = A  + bz * aStride;
    const float* Bb = Bm + bz * bStride;
    float*       Cb = C  + bz * cStride;
    int t = threadIdx.x;
    int tx = t & 15, ty = t >> 4;
    int row0 = blockIdx.y * TILE, col0 = blockIdx.x * TILE;
    int lr = t >> 2, lk = (t & 3) << 2;
    int lk16 = t >> 4;
    int li   = (t & 15) << 2;
    const float* Ap = Ab + (size_t)(row0 + lr) * lda + lk;
    float acc[4][4] = {};
    for (int k0 = 0; k0 < K; k0 += BKK) {
        float4 av = *(const float4*)(Ap + k0);
        float4 bv = *(const float4*)(Bb + (size_t)(k0 + lk16) * ldb + col0 + li);
        __syncthreads();
        As[(lk+0)*LDP+lr]=av.x; As[(lk+1)*LDP+lr]=av.y; As[(lk+2)*LDP+lr]=av.z; As[(lk+3)*LDP+lr]=av.w;
        *(float4*)(Bs + lk16*LDP + li) = bv;
        __syncthreads();
        tile_compute(As, Bs, tx, ty, acc);
    }
#pragma unroll
    for (int i = 0; i < 4; ++i) {
        float4 o = make_float4(acc[i][0], acc[i][1], acc[i][2], acc[i][3]);
        *(float4*)(Cb + (size_t)(row0 + ty*4 + i) * ldc + col0 + tx*4) = o;
    }
}

// ---------------------------------------------------------------------------
extern "C" void kernel_launch(void* const* d_in, const int* in_sizes, int n_in,
                              void* d_out, int out_size, void* d_ws, size_t ws_size,
                              hipStream_t stream) {
    const float* x    = (const float*)d_in[0];   // (8,1024,768)
    const float* phi  = (const float*)d_in[1];   // (64,16,768)
    const float* ln_g = (const float*)d_in[2];   // (64,768)
    const float* ln_b = (const float*)d_in[3];   // (64,768)
    const float* w1   = (const float*)d_in[4];   // (64,768,1536)
    const float* b1   = (const float*)d_in[5];   // (64,1536)
    const float* w2   = (const float*)d_in[6];   // (64,1536,768)
    const float* b2   = (const float*)d_in[7];   // (64,768)
    float* out = (float*)d_out;                  // (8,1024,768)

    float* ws = (float*)d_ws;
    float* phin   = ws;                              // 786432
    float* logits = phin   + 786432;                 // 8388608  (becomes D in place)
    float* Cbuf   = logits + 8388608;                // 8388608
    float* Xs     = Cbuf   + 8388608;                // 6291456  (becomes hdn in place)
    float* h1     = Xs     + 6291456;                // 12582912
    float* Ys     = h1     + 12582912;               // 6291456
    float* pm     = Ys     + 6291456;                // 65536
    float* pl     = pm     + 65536;                  // 65536
    float* fm     = pl     + 65536;                  // 8192
    float* fl     = fm     + 8192;                   // 8192

    // 0) normalize phi over expert axis
    phi_norm_kernel<<<48, 256, 0, stream>>>(phi, phin);

    // 1) logits[b*m, s] = x @ phin^T   (M=8192, N=1024, K=768)
    gemm_nt_kernel<<<dim3(S/TILE, (B*M)/TILE), 256, 0, stream>>>(x, phin, logits, B*M, S, D);

    // 2) C = softmax over slots (rows of logits)
    softmax_row_kernel<<<B*M, 256, 0, stream>>>(logits, Cbuf);

    // 3) D = softmax over tokens (columns), in-place on logits
    colsm_partial_kernel<<<256, 256, 0, stream>>>(logits, pm, pl);
    colsm_combine_kernel<<<32, 256, 0, stream>>>(pm, pl, fm, fl);
    colsm_norm_kernel<<<8192, 256, 0, stream>>>(logits, fm, fl);

    // 4) Xs_b[s,d] = D_b^T @ x_b      (M=1024, N=768, K=1024, batched over b)
    gemm_tn_batched_kernel<<<dim3(D/TILE, S/TILE, B), 256, 0, stream>>>(
        logits, x, Xs, S, D, M, S, D, D,
        (size_t)M * S, (size_t)M * D, (size_t)S * D);

    // 5) LayerNorm in place
    layernorm_kernel<<<B*S, 256, 0, stream>>>(Xs, ln_g, ln_b);

    // 6) h1 = gelu(hdn @ w1 + b1)     (per expert: M=128, N=1536, K=768)
    expert_mlp1_kernel<<<dim3(H/TILE, 128/TILE, NEXP), 256, 0, stream>>>(Xs, w1, b1, h1);

    // 7) Ys = h1 @ w2 + b2, scattered to [b, s, d]  (per expert: M=128, N=768, K=1536)
    expert_mlp2_kernel<<<dim3(D/TILE, 128/TILE, NEXP), 256, 0, stream>>>(h1, w2, b2, Ys);

    // 8) Y_b = C_b @ Ys_b             (M=1024, N=768, K=1024, batched over b)
    gemm_nn_batched_kernel<<<dim3(D/TILE, M/TILE, B), 256, 0, stream>>>(
        Cbuf, Ys, out, M, D, S, S, D, D,
        (size_t)M * S, (size_t)S * D, (size_t)M * D);
}

// Round 2
// 924.048 us; speedup vs baseline: 1.7012x; 1.7012x over previous
//
#include <hip/hip_runtime.h>
#include <math.h>

// Problem constants
#define B 8
#define M 1024
#define D 768
#define NEXP 64
#define P 16
#define H 1536
#define S 1024          // n*p slots
#define EPS_NORM 1e-6f
#define EPS_LN   1e-5f

typedef unsigned short u16;
typedef __attribute__((ext_vector_type(8))) short bf16x8;
typedef __attribute__((ext_vector_type(4))) float f32x4;

__device__ __forceinline__ u16 f2bf(float f) {
    union { float f; unsigned u; } v; v.f = f;
    unsigned r = v.u + 0x7FFFu + ((v.u >> 16) & 1u);   // RNE
    return (u16)(r >> 16);
}

__device__ __forceinline__ float gelu_exact(float x) {
    return 0.5f * x * (1.0f + erff(x * 0.70710678118654752440f));
}

#define GLL16(g, l) __builtin_amdgcn_global_load_lds( \
    (const __attribute__((address_space(1))) void*)(g), \
    (__attribute__((address_space(3))) void*)(l), 16, 0, 0)

// ---------------------------------------------------------------------------
// Shared MFMA GEMM core: 128x128 block tile, BK=32, bf16 NT inputs.
// A: [128 rows][K] row-major bf16 (k contiguous); B: [128 cols][K] likewise.
// 4 waves in 2x2, each wave 64x64 = 4x4 tiles of 16x16x32 MFMA.
__device__ __forceinline__ void mfma_core_128(const u16* __restrict__ Ag,
                                              const u16* __restrict__ Bg,
                                              int K, u16* As, u16* Bs,
                                              f32x4 (&acc)[4][4]) {
    const int t    = threadIdx.x;
    const int lane = t & 63;
    const int wave = t >> 6;
    const int wr   = (wave >> 1) << 6;
    const int wc   = (wave & 1) << 6;
    const int quad = lane >> 4;
    const int l16  = lane & 15;
    // staging: chunk c (0..511) = 16B = (row=c>>2, part=c&3); thread does c=t and c=t+256
    const u16* ga0 = Ag + (size_t)(t >> 2) * K + (t & 3) * 8;
    const u16* ga1 = ga0 + (size_t)64 * K;
    const u16* gb0 = Bg + (size_t)(t >> 2) * K + (t & 3) * 8;
    const u16* gb1 = gb0 + (size_t)64 * K;
    u16* la0 = As + t * 8;
    u16* la1 = la0 + 2048;
    u16* lb0 = Bs + t * 8;
    u16* lb1 = lb0 + 2048;
    const u16* arp = As + (wr + l16) * 32 + quad * 8;
    const u16* brp = Bs + (wc + l16) * 32 + quad * 8;
    for (int k0 = 0; k0 < K; k0 += 32) {
        __syncthreads();              // protect LDS from overwrite
        GLL16(ga0 + k0, la0);
        GLL16(ga1 + k0, la1);
        GLL16(gb0 + k0, lb0);
        GLL16(gb1 + k0, lb1);
        __syncthreads();              // vmcnt drained by compiler before barrier
        bf16x8 af[4], bfr[4];
#pragma unroll
        for (int i = 0; i < 4; ++i) af[i]  = *(const bf16x8*)(arp + i * 512);
#pragma unroll
        for (int j = 0; j < 4; ++j) bfr[j] = *(const bf16x8*)(brp + j * 512);
#pragma unroll
        for (int i = 0; i < 4; ++i)
#pragma unroll
            for (int j = 0; j < 4; ++j)
                acc[i][j] = __builtin_amdgcn_mfma_f32_16x16x32_bf16(af[i], bfr[j], acc[i][j], 0, 0, 0);
    }
}

#define EPI_VARS \
    const int t = threadIdx.x; const int lane = t & 63; const int wave = t >> 6; \
    const int wr = (wave >> 1) << 6; const int wc = (wave & 1) << 6; \
    const int quad = lane >> 4; const int l16 = lane & 15; (void)t;

// ---------------------------------------------------------------------------
// Elementwise / conversion kernels
// ---------------------------------------------------------------------------

// x fp32 -> bf16 row-major
__global__ __launch_bounds__(256) void cvt_x_kernel(const float* __restrict__ x,
                                                    u16* __restrict__ xb) {
    size_t i = ((size_t)blockIdx.x * 256 + threadIdx.x) * 4;
    float4 v = *(const float4*)(x + i);
    ushort4 o;
    o.x = f2bf(v.x); o.y = f2bf(v.y); o.z = f2bf(v.z); o.w = f2bf(v.w);
    *(ushort4*)(xb + i) = o;
}

// phi_n = phi * rsqrt(sum_n phi^2 + eps), write bf16 [s][d]
__global__ __launch_bounds__(256) void phi_norm_kernel(const float* __restrict__ phi,
                                                       u16* __restrict__ phinb) {
    int pos = blockIdx.x * 256 + threadIdx.x;   // 0..P*D-1
    float ss = 0.f;
#pragma unroll 4
    for (int nn = 0; nn < NEXP; ++nn) {
        float v = phi[nn * (P*D) + pos];
        ss += v * v;
    }
    float r = rsqrtf(ss + EPS_NORM);
#pragma unroll 4
    for (int nn = 0; nn < NEXP; ++nn)
        phinb[nn * (P*D) + pos] = f2bf(phi[nn * (P*D) + pos] * r);
}

// generic batched transpose+convert: in fp32 [R][C] -> out bf16 [C][R]
__global__ __launch_bounds__(256) void transpose_cvt_kernel(const float* __restrict__ in,
                                                            u16* __restrict__ out,
                                                            int R, int C,
                                                            size_t inStride, size_t outStride) {
    __shared__ float tile[64][65];
    const float* inb = in + (size_t)blockIdx.z * inStride;
    u16* outb = out + (size_t)blockIdx.z * outStride;
    int r0 = blockIdx.y * 64, c0 = blockIdx.x * 64;
    int tt = threadIdx.x;
    int rr = tt >> 4, c4 = (tt & 15) * 4;
#pragma unroll
    for (int i = 0; i < 4; ++i) {
        float4 v = *(const float4*)(inb + (size_t)(r0 + rr + i*16) * C + c0 + c4);
        tile[rr + i*16][c4 + 0] = v.x;
        tile[rr + i*16][c4 + 1] = v.y;
        tile[rr + i*16][c4 + 2] = v.z;
        tile[rr + i*16][c4 + 3] = v.w;
    }
    __syncthreads();
    int cr = tt >> 4, r4 = (tt & 15) * 4;
#pragma unroll
    for (int i = 0; i < 4; ++i) {
        int crow = cr + i * 16;
        ushort4 o;
        o.x = f2bf(tile[r4 + 0][crow]);
        o.y = f2bf(tile[r4 + 1][crow]);
        o.z = f2bf(tile[r4 + 2][crow]);
        o.w = f2bf(tile[r4 + 3][crow]);
        *(ushort4*)(outb + (size_t)(c0 + crow) * R + r0 + r4) = o;
    }
}

// ---------------------------------------------------------------------------
// GEMM kernels
// ---------------------------------------------------------------------------

// logits[b*m][s] = xb[b*m][d] . phinb[s][d]^T   (fp32 out)
__global__ __launch_bounds__(256) void gemm_logits_mfma(const u16* __restrict__ xb,
                                                        const u16* __restrict__ phinb,
                                                        float* __restrict__ logits) {
    __shared__ __align__(16) u16 As[4096], Bs[4096];
    f32x4 acc[4][4];
#pragma unroll
    for (int i = 0; i < 4; ++i)
#pragma unroll
        for (int j = 0; j < 4; ++j) acc[i][j] = (f32x4){0.f, 0.f, 0.f, 0.f};
    const int row0 = blockIdx.y * 128, col0 = blockIdx.x * 128;
    mfma_core_128(xb + (size_t)row0 * D, phinb + (size_t)col0 * D, D, As, Bs, acc);
    EPI_VARS;
#pragma unroll
    for (int i = 0; i < 4; ++i)
#pragma unroll
        for (int j = 0; j < 4; ++j) {
            int col = col0 + wc + j*16 + l16;
#pragma unroll
            for (int r = 0; r < 4; ++r) {
                int row = row0 + wr + i*16 + quad*4 + r;
                logits[(size_t)row * S + col] = acc[i][j][r];
            }
        }
}

// Xs[b][s][d] = sum_m DT[b][s][m] * xT[b][d][m]   (fp32 out)
__global__ __launch_bounds__(256) void gemm_dispatch_mfma(const u16* __restrict__ DT,
                                                          const u16* __restrict__ xT,
                                                          float* __restrict__ Xs) {
    __shared__ __align__(16) u16 As[4096], Bs[4096];
    f32x4 acc[4][4];
#pragma unroll
    for (int i = 0; i < 4; ++i)
#pragma unroll
        for (int j = 0; j < 4; ++j) acc[i][j] = (f32x4){0.f, 0.f, 0.f, 0.f};
    const int b = blockIdx.z;
    const int row0 = blockIdx.y * 128, col0 = blockIdx.x * 128;
    mfma_core_128(DT + ((size_t)b * S + row0) * M,
                  xT + ((size_t)b * D + col0) * M, M, As, Bs, acc);
    EPI_VARS;
#pragma unroll
    for (int i = 0; i < 4; ++i)
#pragma unroll
        for (int j = 0; j < 4; ++j) {
            int col = col0 + wc + j*16 + l16;
#pragma unroll
            for (int r = 0; r < 4; ++r) {
                int row = row0 + wr + i*16 + quad*4 + r;
                Xs[((size_t)b * S + row) * D + col] = acc[i][j][r];
            }
        }
}

// h1[n][r][h] = gelu(hdnE[n][r][:] . w1T[n][h][:] + b1[n][h])  (bf16 out)
__global__ __launch_bounds__(256) void gemm_mlp1_mfma(const u16* __restrict__ hdnE,
                                                      const u16* __restrict__ w1T,
                                                      const float* __restrict__ b1,
                                                      u16* __restrict__ h1) {
    __shared__ __align__(16) u16 As[4096], Bs[4096];
    f32x4 acc[4][4];
#pragma unroll
    for (int i = 0; i < 4; ++i)
#pragma unroll
        for (int j = 0; j < 4; ++j) acc[i][j] = (f32x4){0.f, 0.f, 0.f, 0.f};
    const int n = blockIdx.z;
    const int col0 = blockIdx.x * 128;
    mfma_core_128(hdnE + (size_t)n * 128 * D,
                  w1T + ((size_t)n * H + col0) * D, D, As, Bs, acc);
    EPI_VARS;
#pragma unroll
    for (int i = 0; i < 4; ++i)
#pragma unroll
        for (int j = 0; j < 4; ++j) {
            int h = col0 + wc + j*16 + l16;
            float bias = b1[n * H + h];
#pragma unroll
            for (int r = 0; r < 4; ++r) {
                int row = wr + i*16 + quad*4 + r;
                h1[((size_t)n * 128 + row) * H + h] = f2bf(gelu_exact(acc[i][j][r] + bias));
            }
        }
}

// YsT[b][d][s] = h1[n][r][:] . w2T[n][d][:] + b2[n][d]   (bf16 out, transposed scatter)
__global__ __launch_bounds__(256) void gemm_mlp2_mfma(const u16* __restrict__ h1,
                                                      const u16* __restrict__ w2T,
                                                      const float* __restrict__ b2,
                                                      u16* __restrict__ YsT) {
    __shared__ __align__(16) u16 As[4096], Bs[4096];
    f32x4 acc[4][4];
#pragma unroll
    for (int i = 0; i < 4; ++i)
#pragma unroll
        for (int j = 0; j < 4; ++j) acc[i][j] = (f32x4){0.f, 0.f, 0.f, 0.f};
    const int n = blockIdx.z;
    const int col0 = blockIdx.x * 128;
    mfma_core_128(h1 + (size_t)n * 128 * H,
                  w2T + ((size_t)n * D + col0) * H, H, As, Bs, acc);
    EPI_VARS;
#pragma unroll
    for (int i = 0; i < 4; ++i)
#pragma unroll
        for (int j = 0; j < 4; ++j) {
            int d = col0 + wc + j*16 + l16;
            float bias = b2[n * D + d];
            // rows wr+i*16+quad*4+{0..3} are 4 consecutive tokens -> same b', consecutive p
            int bb = ((wr + i*16) >> 4);          // batch index 0..7
            int p0 = quad * 4;
            ushort4 o;
            o.x = f2bf(acc[i][j][0] + bias);
            o.y = f2bf(acc[i][j][1] + bias);
            o.z = f2bf(acc[i][j][2] + bias);
            o.w = f2bf(acc[i][j][3] + bias);
            *(ushort4*)(YsT + ((size_t)bb * D + d) * S + n * P + p0) = o;
        }
}

// out[b][m][d] = sum_s Cb[b][m][s] * YsT[b][d][s]   (fp32 out)
__global__ __launch_bounds__(256) void gemm_combine_mfma(const u16* __restrict__ Cb,
                                                         const u16* __restrict__ YsT,
                                                         float* __restrict__ out) {
    __shared__ __align__(16) u16 As[4096], Bs[4096];
    f32x4 acc[4][4];
#pragma unroll
    for (int i = 0; i < 4; ++i)
#pragma unroll
        for (int j = 0; j < 4; ++j) acc[i][j] = (f32x4){0.f, 0.f, 0.f, 0.f};
    const int b = blockIdx.z;
    const int row0 = blockIdx.y * 128, col0 = blockIdx.x * 128;
    mfma_core_128(Cb + ((size_t)b * M + row0) * S,
                  YsT + ((size_t)b * D + col0) * S, S, As, Bs, acc);
    EPI_VARS;
#pragma unroll
    for (int i = 0; i < 4; ++i)
#pragma unroll
        for (int j = 0; j < 4; ++j) {
            int col = col0 + wc + j*16 + l16;
#pragma unroll
            for (int r = 0; r < 4; ++r) {
                int row = row0 + wr + i*16 + quad*4 + r;
                out[((size_t)b * M + row) * D + col] = acc[i][j][r];
            }
        }
}

// ---------------------------------------------------------------------------
// Softmax / LN kernels
// ---------------------------------------------------------------------------

// row softmax over 1024 slots; fp32 in, bf16 out (C matrix)
__global__ __launch_bounds__(256) void softmax_row_kernel(const float* __restrict__ in,
                                                          u16* __restrict__ outb) {
    __shared__ float red[4], red2[4];
    int row = blockIdx.x;
    int t = threadIdx.x;
    const float* rp = in + (size_t)row * S;
    float4 v = *(const float4*)(rp + t*4);
    float mx = fmaxf(fmaxf(v.x, v.y), fmaxf(v.z, v.w));
#pragma unroll
    for (int o = 1; o < 64; o <<= 1) mx = fmaxf(mx, __shfl_xor(mx, o));
    if ((t & 63) == 0) red[t >> 6] = mx;
    __syncthreads();
    mx = fmaxf(fmaxf(red[0], red[1]), fmaxf(red[2], red[3]));
    float4 e;
    e.x = expf(v.x - mx); e.y = expf(v.y - mx); e.z = expf(v.z - mx); e.w = expf(v.w - mx);
    float sum = e.x + e.y + e.z + e.w;
#pragma unroll
    for (int o = 1; o < 64; o <<= 1) sum += __shfl_xor(sum, o);
    if ((t & 63) == 0) red2[t >> 6] = sum;
    __syncthreads();
    sum = red2[0] + red2[1] + red2[2] + red2[3];
    float inv = 1.f / sum;
    ushort4 o4;
    o4.x = f2bf(e.x * inv); o4.y = f2bf(e.y * inv);
    o4.z = f2bf(e.z * inv); o4.w = f2bf(e.w * inv);
    *(ushort4*)(outb + (size_t)row * S + t*4) = o4;
}

// column softmax over tokens m: phase 1 partials (8 chunks of 128 rows)
__global__ __launch_bounds__(256) void colsm_partial_kernel(const float* __restrict__ logits,
                                                            float* __restrict__ pm,
                                                            float* __restrict__ pl) {
    int gid = blockIdx.x * 256 + threadIdx.x;    // 0..65535
    int c   = gid >> 13;                         // 0..7
    int col = gid & 8191;                        // b*S + s
    int b = col >> 10, s = col & (S - 1);
    const float* base = logits + ((size_t)b << 20) + ((size_t)(c * 128) << 10) + s;
    float mx = -INFINITY, l = 0.f;
    for (int m = 0; m < 128; ++m) {
        float v = base[(size_t)m << 10];
        float nm = fmaxf(mx, v);
        l = l * expf(mx - nm) + expf(v - nm);
        mx = nm;
    }
    pm[gid] = mx;
    pl[gid] = l;
}

__global__ __launch_bounds__(256) void colsm_combine_kernel(const float* __restrict__ pm,
                                                            const float* __restrict__ pl,
                                                            float* __restrict__ fm,
                                                            float* __restrict__ fl) {
    int col = blockIdx.x * 256 + threadIdx.x;    // 0..8191
    float mx = -INFINITY;
#pragma unroll
    for (int c = 0; c < 8; ++c) mx = fmaxf(mx, pm[c * 8192 + col]);
    float l = 0.f;
#pragma unroll
    for (int c = 0; c < 8; ++c) l += pl[c * 8192 + col] * expf(pm[c * 8192 + col] - mx);
    fm[col] = mx;
    fl[col] = 1.f / l;
}

// phase 3: normalize + transpose -> DT[b][s][m] bf16
__global__ __launch_bounds__(256) void dt_transpose_kernel(const float* __restrict__ logits,
                                                           const float* __restrict__ fm,
                                                           const float* __restrict__ fl,
                                                           u16* __restrict__ DT) {
    __shared__ float tile[64][65];
    int b = blockIdx.z;
    int m0 = blockIdx.y * 64, s0 = blockIdx.x * 64;
    int tt = threadIdx.x;
    int rr = tt >> 4, c4 = (tt & 15) * 4;
    float4 fmv = *(const float4*)(fm + (size_t)b * S + s0 + c4);
    float4 flv = *(const float4*)(fl + (size_t)b * S + s0 + c4);
#pragma unroll
    for (int i = 0; i < 4; ++i) {
        float4 v = *(const float4*)(logits + ((size_t)b * M + m0 + rr + i*16) * S + s0 + c4);
        tile[rr + i*16][c4 + 0] = expf(v.x - fmv.x) * flv.x;
        tile[rr + i*16][c4 + 1] = expf(v.y - fmv.y) * flv.y;
        tile[rr + i*16][c4 + 2] = expf(v.z - fmv.z) * flv.z;
        tile[rr + i*16][c4 + 3] = expf(v.w - fmv.w) * flv.w;
    }
    __syncthreads();
    int cr = tt >> 4, r4 = (tt & 15) * 4;
#pragma unroll
    for (int i = 0; i < 4; ++i) {
        int crow = cr + i * 16;       // s index within tile
        ushort4 o;
        o.x = f2bf(tile[r4 + 0][crow]);
        o.y = f2bf(tile[r4 + 1][crow]);
        o.z = f2bf(tile[r4 + 2][crow]);
        o.w = f2bf(tile[r4 + 3][crow]);
        *(ushort4*)(DT + ((size_t)b * S + s0 + crow) * M + m0 + r4) = o;
    }
}

// LayerNorm rows of Xs (fp32) -> hdnE bf16 in expert-major layout [n][b*16+p][d]
__global__ __launch_bounds__(256) void layernorm_kernel(const float* __restrict__ Xs,
                                                        const float* __restrict__ g,
                                                        const float* __restrict__ bt,
                                                        u16* __restrict__ hdnE) {
    __shared__ float rs[4], rq[4];
    int row = blockIdx.x;                  // b*1024 + n*16 + p
    int b = row >> 10;
    int n = (row >> 4) & (NEXP - 1);
    int p = row & 15;
    const float* rp = Xs + (size_t)row * D;
    u16* op = hdnE + ((size_t)n * 128 + b * 16 + p) * D;
    int t = threadIdx.x;
    float x0 = rp[t], x1 = rp[t + 256], x2 = rp[t + 512];
    float s  = x0 + x1 + x2;
    float sq = x0*x0 + x1*x1 + x2*x2;
#pragma unroll
    for (int o = 1; o < 64; o <<= 1) { s += __shfl_xor(s, o); sq += __shfl_xor(sq, o); }
    if ((t & 63) == 0) { rs[t >> 6] = s; rq[t >> 6] = sq; }
    __syncthreads();
    s  = rs[0] + rs[1] + rs[2] + rs[3];
    sq = rq[0] + rq[1] + rq[2] + rq[3];
    float mu  = s * (1.f / D);
    float var = sq * (1.f / D) - mu * mu;
    float inv = rsqrtf(var + EPS_LN);
    const float* gn = g  + n * D;
    const float* bn = bt + n * D;
    op[t]       = f2bf((x0 - mu) * inv * gn[t]       + bn[t]);
    op[t + 256] = f2bf((x1 - mu) * inv * gn[t + 256] + bn[t + 256]);
    op[t + 512] = f2bf((x2 - mu) * inv * gn[t + 512] + bn[t + 512]);
}

// ---------------------------------------------------------------------------
extern "C" void kernel_launch(void* const* d_in, const int* in_sizes, int n_in,
                              void* d_out, int out_size, void* d_ws, size_t ws_size,
                              hipStream_t stream) {
    const float* x    = (const float*)d_in[0];
    const float* phi  = (const float*)d_in[1];
    const float* ln_g = (const float*)d_in[2];
    const float* ln_b = (const float*)d_in[3];
    const float* w1   = (const float*)d_in[4];
    const float* b1   = (const float*)d_in[5];
    const float* w2   = (const float*)d_in[6];
    const float* b2   = (const float*)d_in[7];
    float* out = (float*)d_out;

    char* ws = (char*)d_ws;
    // byte offsets (all 256-aligned); several regions are reused over time
    u16*   wT     = (u16*)(ws + 0);                 // 151.0 MB (w1T, then w2T)
    float* logits = (float*)(ws + 150994944);       // 33.6 MB (later reused as Xs fp32)
    u16*   Cb     = (u16*)(ws + 184549376);         // 16.8 MB
    u16*   xb     = (u16*)(ws + 201326592);         // 12.6 MB (xb+DT later reused as h1)
    u16*   DT     = (u16*)(ws + 213909504);         // 16.8 MB
    u16*   xTb    = (u16*)(ws + 230686720);         // 12.6 MB (later reused as YsT)
    u16*   phinb  = (u16*)(ws + 243269632);         //  1.6 MB
    u16*   hdnE   = (u16*)(ws + 244842496);         // 12.6 MB
    float* pm     = (float*)(ws + 257425408);
    float* pl     = (float*)(ws + 257687552);
    float* fm     = (float*)(ws + 257949696);
    float* fl     = (float*)(ws + 257982464);
    float* Xs     = logits;                         // overlay (logits dead by then)
    u16*   h1     = xb;                             // overlay (xb+DT dead by then)
    u16*   YsT    = xTb;                            // overlay (xTb dead by then)

    // --- operand preparation ---
    cvt_x_kernel<<<6144, 256, 0, stream>>>(x, xb);
    phi_norm_kernel<<<48, 256, 0, stream>>>(phi, phinb);
    // xT[b][d][m]: per-b transpose of x[m][d] (R=1024 rows m, C=768 cols d)
    transpose_cvt_kernel<<<dim3(12, 16, B), 256, 0, stream>>>(
        x, xTb, M, D, (size_t)M * D, (size_t)D * M);
    // w1T[n][h][d]: transpose of w1[n][d][h] (R=768, C=1536)
    transpose_cvt_kernel<<<dim3(24, 12, NEXP), 256, 0, stream>>>(
        w1, wT, D, H, (size_t)D * H, (size_t)H * D);

    // --- routing ---
    gemm_logits_mfma<<<dim3(8, 64), 256, 0, stream>>>(xb, phinb, logits);
    softmax_row_kernel<<<B * M, 256, 0, stream>>>(logits, Cb);
    colsm_partial_kernel<<<256, 256, 0, stream>>>(logits, pm, pl);
    colsm_combine_kernel<<<32, 256, 0, stream>>>(pm, pl, fm, fl);
    dt_transpose_kernel<<<dim3(16, 16, B), 256, 0, stream>>>(logits, fm, fl, DT);

    // --- dispatch ---
    gemm_dispatch_mfma<<<dim3(6, 8, B), 256, 0, stream>>>(DT, xTb, Xs);
    layernorm_kernel<<<B * S, 256, 0, stream>>>(Xs, ln_g, ln_b, hdnE);

    // --- expert MLP ---
    gemm_mlp1_mfma<<<dim3(12, 1, NEXP), 256, 0, stream>>>(hdnE, wT, b1, h1);
    // w2T[n][d][h]: transpose of w2[n][h][d] (R=1536, C=768), into same buffer (after mlp1)
    transpose_cvt_kernel<<<dim3(12, 24, NEXP), 256, 0, stream>>>(
        w2, wT, H, D, (size_t)H * D, (size_t)D * H);
    gemm_mlp2_mfma<<<dim3(6, 1, NEXP), 256, 0, stream>>>(h1, wT, b2, YsT);

    // --- combine ---
    gemm_combine_mfma<<<dim3(6, 8, B), 256, 0, stream>>>(Cb, YsT, out);
}

// Round 3
// 795.818 us; speedup vs baseline: 1.9753x; 1.1611x over previous
//
#include <hip/hip_runtime.h>
#include <math.h>

// Problem constants
#define B 8
#define M 1024
#define D 768
#define NEXP 64
#define P 16
#define H 1536
#define S 1024          // n*p slots
#define EPS_NORM 1e-6f
#define EPS_LN   1e-5f

typedef unsigned short u16;
typedef __attribute__((ext_vector_type(8))) short bf16x8;
typedef __attribute__((ext_vector_type(4))) float f32x4;

__device__ __forceinline__ u16 f2bf(float f) {
    union { float f; unsigned u; } v; v.f = f;
    unsigned r = v.u + 0x7FFFu + ((v.u >> 16) & 1u);   // RNE
    return (u16)(r >> 16);
}

__device__ __forceinline__ float gelu_exact(float x) {
    return 0.5f * x * (1.0f + erff(x * 0.70710678118654752440f));
}

#define GLL16(g, l) __builtin_amdgcn_global_load_lds( \
    (const __attribute__((address_space(1))) void*)(g), \
    (__attribute__((address_space(3))) void*)(l), 16, 0, 0)

// ---------------------------------------------------------------------------
// MFMA GEMM core (NT, both operands bf16 k-contiguous): 128x128 tile, BK=32.
__device__ __forceinline__ void mfma_core_128(const u16* __restrict__ Ag,
                                              const u16* __restrict__ Bg,
                                              int K, u16* As, u16* Bs,
                                              f32x4 (&acc)[4][4]) {
    const int t    = threadIdx.x;
    const int lane = t & 63;
    const int wave = t >> 6;
    const int wr   = (wave >> 1) << 6;
    const int wc   = (wave & 1) << 6;
    const int quad = lane >> 4;
    const int l16  = lane & 15;
    const u16* ga0 = Ag + (size_t)(t >> 2) * K + (t & 3) * 8;
    const u16* ga1 = ga0 + (size_t)64 * K;
    const u16* gb0 = Bg + (size_t)(t >> 2) * K + (t & 3) * 8;
    const u16* gb1 = gb0 + (size_t)64 * K;
    u16* la0 = As + t * 8;
    u16* la1 = la0 + 2048;
    u16* lb0 = Bs + t * 8;
    u16* lb1 = lb0 + 2048;
    const u16* arp = As + (wr + l16) * 32 + quad * 8;
    const u16* brp = Bs + (wc + l16) * 32 + quad * 8;
    for (int k0 = 0; k0 < K; k0 += 32) {
        __syncthreads();
        GLL16(ga0 + k0, la0);
        GLL16(ga1 + k0, la1);
        GLL16(gb0 + k0, lb0);
        GLL16(gb1 + k0, lb1);
        __syncthreads();
        bf16x8 af[4], bfr[4];
#pragma unroll
        for (int i = 0; i < 4; ++i) af[i]  = *(const bf16x8*)(arp + i * 512);
#pragma unroll
        for (int j = 0; j < 4; ++j) bfr[j] = *(const bf16x8*)(brp + j * 512);
#pragma unroll
        for (int i = 0; i < 4; ++i)
#pragma unroll
            for (int j = 0; j < 4; ++j)
                acc[i][j] = __builtin_amdgcn_mfma_f32_16x16x32_bf16(af[i], bfr[j], acc[i][j], 0, 0, 0);
    }
}

// ---------------------------------------------------------------------------
// MFMA GEMM core, A bf16 NT (k-contig), B fp32 NATIVE k-major [K][ldb] read
// directly from global (weights). B is converted + transposed into LDS
// [col][k] (stride 40 u16 for 16B-aligned b128 fragment reads).
__device__ __forceinline__ void mfma_core_bf32(const u16* __restrict__ Ag, int K,
                                               const float* __restrict__ Bg, int ldb,
                                               u16* As, u16* Bs,
                                               f32x4 (&acc)[4][4]) {
    const int t    = threadIdx.x;
    const int lane = t & 63;
    const int wave = t >> 6;
    const int wr   = (wave >> 1) << 6;
    const int wc   = (wave & 1) << 6;
    const int quad = lane >> 4;
    const int l16  = lane & 15;
    const u16* ga0 = Ag + (size_t)(t >> 2) * K + (t & 3) * 8;
    const u16* ga1 = ga0 + (size_t)64 * K;
    u16* la0 = As + t * 8;
    u16* la1 = la0 + 2048;
    const int bcol = t & 127;          // tile-local column
    const int kq   = (t >> 7) << 4;    // 0 or 16: k-group base
    const float* bg0 = Bg + (size_t)kq * ldb + bcol;
    u16* lb = Bs + bcol * 40 + kq;
    const u16* arp = As + (wr + l16) * 32 + quad * 8;
    const u16* brp = Bs + (wc + l16) * 40 + quad * 8;
    for (int k0 = 0; k0 < K; k0 += 32) {
        const float* bg = bg0 + (size_t)k0 * ldb;
        __syncthreads();
        GLL16(ga0 + k0, la0);
        GLL16(ga1 + k0, la1);
        // B: 16 k-strided fp32 loads (coalesced across lanes), cvt, transpose-write
        float f[16];
#pragma unroll
        for (int i = 0; i < 16; ++i) f[i] = bg[(size_t)i * ldb];
#pragma unroll
        for (int i = 0; i < 4; ++i) {
            ushort4 o;
            o.x = f2bf(f[i*4 + 0]); o.y = f2bf(f[i*4 + 1]);
            o.z = f2bf(f[i*4 + 2]); o.w = f2bf(f[i*4 + 3]);
            *(ushort4*)(lb + i * 4) = o;
        }
        __syncthreads();
        bf16x8 af[4], bfr[4];
#pragma unroll
        for (int i = 0; i < 4; ++i) af[i]  = *(const bf16x8*)(arp + i * 512);
#pragma unroll
        for (int j = 0; j < 4; ++j) bfr[j] = *(const bf16x8*)(brp + j * 640);
#pragma unroll
        for (int i = 0; i < 4; ++i)
#pragma unroll
            for (int j = 0; j < 4; ++j)
                acc[i][j] = __builtin_amdgcn_mfma_f32_16x16x32_bf16(af[i], bfr[j], acc[i][j], 0, 0, 0);
    }
}

#define EPI_VARS \
    const int t = threadIdx.x; const int lane = t & 63; const int wave = t >> 6; \
    const int wr = (wave >> 1) << 6; const int wc = (wave & 1) << 6; \
    const int quad = lane >> 4; const int l16 = lane & 15; (void)t;

#define ACC_INIT \
    f32x4 acc[4][4]; \
    _Pragma("unroll") for (int i = 0; i < 4; ++i) \
    _Pragma("unroll") for (int j = 0; j < 4; ++j) acc[i][j] = (f32x4){0.f, 0.f, 0.f, 0.f};

// ---------------------------------------------------------------------------
// x prep: one read of x -> xb (bf16 [b][m][d]) + xT (bf16 [b][d][m])
__global__ __launch_bounds__(256) void xprep_kernel(const float* __restrict__ x,
                                                    u16* __restrict__ xb,
                                                    u16* __restrict__ xT) {
    __shared__ float tile[64][65];
    int b = blockIdx.z;
    int m0 = blockIdx.y * 64, d0 = blockIdx.x * 64;
    int tt = threadIdx.x;
    int rr = tt >> 4, c4 = (tt & 15) * 4;
#pragma unroll
    for (int i = 0; i < 4; ++i) {
        int m = m0 + rr + i * 16;
        float4 v = *(const float4*)(x + ((size_t)b * M + m) * D + d0 + c4);
        tile[rr + i*16][c4 + 0] = v.x;
        tile[rr + i*16][c4 + 1] = v.y;
        tile[rr + i*16][c4 + 2] = v.z;
        tile[rr + i*16][c4 + 3] = v.w;
        ushort4 o;
        o.x = f2bf(v.x); o.y = f2bf(v.y); o.z = f2bf(v.z); o.w = f2bf(v.w);
        *(ushort4*)(xb + ((size_t)b * M + m) * D + d0 + c4) = o;
    }
    __syncthreads();
    int cr = tt >> 4, r4 = (tt & 15) * 4;
#pragma unroll
    for (int i = 0; i < 4; ++i) {
        int crow = cr + i * 16;       // d index within tile
        ushort4 o;
        o.x = f2bf(tile[r4 + 0][crow]);
        o.y = f2bf(tile[r4 + 1][crow]);
        o.z = f2bf(tile[r4 + 2][crow]);
        o.w = f2bf(tile[r4 + 3][crow]);
        *(ushort4*)(xT + ((size_t)b * D + d0 + crow) * M + m0 + r4) = o;
    }
}

// phi_n = phi * rsqrt(sum_n phi^2 + eps), write bf16 [s][d]
__global__ __launch_bounds__(256) void phi_norm_kernel(const float* __restrict__ phi,
                                                       u16* __restrict__ phinb) {
    int pos = blockIdx.x * 256 + threadIdx.x;   // 0..P*D-1
    float ss = 0.f;
#pragma unroll 4
    for (int nn = 0; nn < NEXP; ++nn) {
        float v = phi[nn * (P*D) + pos];
        ss += v * v;
    }
    float r = rsqrtf(ss + EPS_NORM);
#pragma unroll 4
    for (int nn = 0; nn < NEXP; ++nn)
        phinb[nn * (P*D) + pos] = f2bf(phi[nn * (P*D) + pos] * r);
}

// ---------------------------------------------------------------------------
// GEMM kernels
// ---------------------------------------------------------------------------

// logits[b*m][s] = xb[b*m][d] . phinb[s][d]^T   (fp32 out)
__global__ __launch_bounds__(256) void gemm_logits_mfma(const u16* __restrict__ xb,
                                                        const u16* __restrict__ phinb,
                                                        float* __restrict__ logits) {
    __shared__ __align__(16) u16 As[4096], Bs[4096];
    ACC_INIT;
    const int row0 = blockIdx.y * 128, col0 = blockIdx.x * 128;
    mfma_core_128(xb + (size_t)row0 * D, phinb + (size_t)col0 * D, D, As, Bs, acc);
    EPI_VARS;
#pragma unroll
    for (int i = 0; i < 4; ++i)
#pragma unroll
        for (int j = 0; j < 4; ++j) {
            int col = col0 + wc + j*16 + l16;
#pragma unroll
            for (int r = 0; r < 4; ++r) {
                int row = row0 + wr + i*16 + quad*4 + r;
                logits[(size_t)row * S + col] = acc[i][j][r];
            }
        }
}

// Xs[b][s][d] = sum_m DT[b][s][m] * xT[b][d][m]   (fp32 out)
__global__ __launch_bounds__(256) void gemm_dispatch_mfma(const u16* __restrict__ DT,
                                                          const u16* __restrict__ xT,
                                                          float* __restrict__ Xs) {
    __shared__ __align__(16) u16 As[4096], Bs[4096];
    ACC_INIT;
    const int b = blockIdx.z;
    const int row0 = blockIdx.y * 128, col0 = blockIdx.x * 128;
    mfma_core_128(DT + ((size_t)b * S + row0) * M,
                  xT + ((size_t)b * D + col0) * M, M, As, Bs, acc);
    EPI_VARS;
#pragma unroll
    for (int i = 0; i < 4; ++i)
#pragma unroll
        for (int j = 0; j < 4; ++j) {
            int col = col0 + wc + j*16 + l16;
#pragma unroll
            for (int r = 0; r < 4; ++r) {
                int row = row0 + wr + i*16 + quad*4 + r;
                Xs[((size_t)b * S + row) * D + col] = acc[i][j][r];
            }
        }
}

// h1[n][r][h] = gelu(hdnE[n][r][:] . w1[n][:][h] + b1[n][h])  (bf16 out)
// B = w1 native [d][h] fp32, consumed directly (k-major).
__global__ __launch_bounds__(256) void gemm_mlp1_mfma(const u16* __restrict__ hdnE,
                                                      const float* __restrict__ w1,
                                                      const float* __restrict__ b1,
                                                      u16* __restrict__ h1) {
    __shared__ __align__(16) u16 As[4096], Bs[5120];
    ACC_INIT;
    const int n = blockIdx.z;
    const int col0 = blockIdx.x * 128;
    mfma_core_bf32(hdnE + (size_t)n * 128 * D, D,
                   w1 + (size_t)n * D * H + col0, H, As, Bs, acc);
    EPI_VARS;
#pragma unroll
    for (int i = 0; i < 4; ++i)
#pragma unroll
        for (int j = 0; j < 4; ++j) {
            int h = col0 + wc + j*16 + l16;
            float bias = b1[n * H + h];
#pragma unroll
            for (int r = 0; r < 4; ++r) {
                int row = wr + i*16 + quad*4 + r;
                h1[((size_t)n * 128 + row) * H + h] = f2bf(gelu_exact(acc[i][j][r] + bias));
            }
        }
}

// YsT[b][d][s] = h1[n][r][:] . w2[n][:][d] + b2[n][d]   (bf16 out, transposed scatter)
// B = w2 native [h][d] fp32, consumed directly (k-major).
__global__ __launch_bounds__(256) void gemm_mlp2_mfma(const u16* __restrict__ h1,
                                                      const float* __restrict__ w2,
                                                      const float* __restrict__ b2,
                                                      u16* __restrict__ YsT) {
    __shared__ __align__(16) u16 As[4096], Bs[5120];
    ACC_INIT;
    const int n = blockIdx.z;
    const int col0 = blockIdx.x * 128;
    mfma_core_bf32(h1 + (size_t)n * 128 * H, H,
                   w2 + (size_t)n * H * D + col0, D, As, Bs, acc);
    EPI_VARS;
#pragma unroll
    for (int i = 0; i < 4; ++i)
#pragma unroll
        for (int j = 0; j < 4; ++j) {
            int d = col0 + wc + j*16 + l16;
            float bias = b2[n * D + d];
            int bb = ((wr + i*16) >> 4);          // batch index 0..7
            int p0 = quad * 4;
            ushort4 o;
            o.x = f2bf(acc[i][j][0] + bias);
            o.y = f2bf(acc[i][j][1] + bias);
            o.z = f2bf(acc[i][j][2] + bias);
            o.w = f2bf(acc[i][j][3] + bias);
            *(ushort4*)(YsT + ((size_t)bb * D + d) * S + n * P + p0) = o;
        }
}

// out[b][m][d] = sum_s Cb[b][m][s] * YsT[b][d][s]   (fp32 out)
__global__ __launch_bounds__(256) void gemm_combine_mfma(const u16* __restrict__ Cb,
                                                         const u16* __restrict__ YsT,
                                                         float* __restrict__ out) {
    __shared__ __align__(16) u16 As[4096], Bs[4096];
    ACC_INIT;
    const int b = blockIdx.z;
    const int row0 = blockIdx.y * 128, col0 = blockIdx.x * 128;
    mfma_core_128(Cb + ((size_t)b * M + row0) * S,
                  YsT + ((size_t)b * D + col0) * S, S, As, Bs, acc);
    EPI_VARS;
#pragma unroll
    for (int i = 0; i < 4; ++i)
#pragma unroll
        for (int j = 0; j < 4; ++j) {
            int col = col0 + wc + j*16 + l16;
#pragma unroll
            for (int r = 0; r < 4; ++r) {
                int row = row0 + wr + i*16 + quad*4 + r;
                out[((size_t)b * M + row) * D + col] = acc[i][j][r];
            }
        }
}

// ---------------------------------------------------------------------------
// Softmax / LN kernels
// ---------------------------------------------------------------------------

__global__ __launch_bounds__(256) void softmax_row_kernel(const float* __restrict__ in,
                                                          u16* __restrict__ outb) {
    __shared__ float red[4], red2[4];
    int row = blockIdx.x;
    int t = threadIdx.x;
    const float* rp = in + (size_t)row * S;
    float4 v = *(const float4*)(rp + t*4);
    float mx = fmaxf(fmaxf(v.x, v.y), fmaxf(v.z, v.w));
#pragma unroll
    for (int o = 1; o < 64; o <<= 1) mx = fmaxf(mx, __shfl_xor(mx, o));
    if ((t & 63) == 0) red[t >> 6] = mx;
    __syncthreads();
    mx = fmaxf(fmaxf(red[0], red[1]), fmaxf(red[2], red[3]));
    float4 e;
    e.x = expf(v.x - mx); e.y = expf(v.y - mx); e.z = expf(v.z - mx); e.w = expf(v.w - mx);
    float sum = e.x + e.y + e.z + e.w;
#pragma unroll
    for (int o = 1; o < 64; o <<= 1) sum += __shfl_xor(sum, o);
    if ((t & 63) == 0) red2[t >> 6] = sum;
    __syncthreads();
    sum = red2[0] + red2[1] + red2[2] + red2[3];
    float inv = 1.f / sum;
    ushort4 o4;
    o4.x = f2bf(e.x * inv); o4.y = f2bf(e.y * inv);
    o4.z = f2bf(e.z * inv); o4.w = f2bf(e.w * inv);
    *(ushort4*)(outb + (size_t)row * S + t*4) = o4;
}

__global__ __launch_bounds__(256) void colsm_partial_kernel(const float* __restrict__ logits,
                                                            float* __restrict__ pm,
                                                            float* __restrict__ pl) {
    int gid = blockIdx.x * 256 + threadIdx.x;    // 0..65535
    int c   = gid >> 13;                         // 0..7
    int col = gid & 8191;                        // b*S + s
    int b = col >> 10, s = col & (S - 1);
    const float* base = logits + ((size_t)b << 20) + ((size_t)(c * 128) << 10) + s;
    float mx = -INFINITY, l = 0.f;
    for (int m = 0; m < 128; ++m) {
        float v = base[(size_t)m << 10];
        float nm = fmaxf(mx, v);
        l = l * expf(mx - nm) + expf(v - nm);
        mx = nm;
    }
    pm[gid] = mx;
    pl[gid] = l;
}

__global__ __launch_bounds__(256) void colsm_combine_kernel(const float* __restrict__ pm,
                                                            const float* __restrict__ pl,
                                                            float* __restrict__ fm,
                                                            float* __restrict__ fl) {
    int col = blockIdx.x * 256 + threadIdx.x;    // 0..8191
    float mx = -INFINITY;
#pragma unroll
    for (int c = 0; c < 8; ++c) mx = fmaxf(mx, pm[c * 8192 + col]);
    float l = 0.f;
#pragma unroll
    for (int c = 0; c < 8; ++c) l += pl[c * 8192 + col] * expf(pm[c * 8192 + col] - mx);
    fm[col] = mx;
    fl[col] = 1.f / l;
}

// normalize + transpose -> DT[b][s][m] bf16
__global__ __launch_bounds__(256) void dt_transpose_kernel(const float* __restrict__ logits,
                                                           const float* __restrict__ fm,
                                                           const float* __restrict__ fl,
                                                           u16* __restrict__ DT) {
    __shared__ float tile[64][65];
    int b = blockIdx.z;
    int m0 = blockIdx.y * 64, s0 = blockIdx.x * 64;
    int tt = threadIdx.x;
    int rr = tt >> 4, c4 = (tt & 15) * 4;
    float4 fmv = *(const float4*)(fm + (size_t)b * S + s0 + c4);
    float4 flv = *(const float4*)(fl + (size_t)b * S + s0 + c4);
#pragma unroll
    for (int i = 0; i < 4; ++i) {
        float4 v = *(const float4*)(logits + ((size_t)b * M + m0 + rr + i*16) * S + s0 + c4);
        tile[rr + i*16][c4 + 0] = expf(v.x - fmv.x) * flv.x;
        tile[rr + i*16][c4 + 1] = expf(v.y - fmv.y) * flv.y;
        tile[rr + i*16][c4 + 2] = expf(v.z - fmv.z) * flv.z;
        tile[rr + i*16][c4 + 3] = expf(v.w - fmv.w) * flv.w;
    }
    __syncthreads();
    int cr = tt >> 4, r4 = (tt & 15) * 4;
#pragma unroll
    for (int i = 0; i < 4; ++i) {
        int crow = cr + i * 16;       // s index within tile
        ushort4 o;
        o.x = f2bf(tile[r4 + 0][crow]);
        o.y = f2bf(tile[r4 + 1][crow]);
        o.z = f2bf(tile[r4 + 2][crow]);
        o.w = f2bf(tile[r4 + 3][crow]);
        *(ushort4*)(DT + ((size_t)b * S + s0 + crow) * M + m0 + r4) = o;
    }
}

// LayerNorm rows of Xs (fp32) -> hdnE bf16 in expert-major layout [n][b*16+p][d]
__global__ __launch_bounds__(256) void layernorm_kernel(const float* __restrict__ Xs,
                                                        const float* __restrict__ g,
                                                        const float* __restrict__ bt,
                                                        u16* __restrict__ hdnE) {
    __shared__ float rs[4], rq[4];
    int row = blockIdx.x;                  // b*1024 + n*16 + p
    int b = row >> 10;
    int n = (row >> 4) & (NEXP - 1);
    int p = row & 15;
    const float* rp = Xs + (size_t)row * D;
    u16* op = hdnE + ((size_t)n * 128 + b * 16 + p) * D;
    int t = threadIdx.x;
    float x0 = rp[t], x1 = rp[t + 256], x2 = rp[t + 512];
    float s  = x0 + x1 + x2;
    float sq = x0*x0 + x1*x1 + x2*x2;
#pragma unroll
    for (int o = 1; o < 64; o <<= 1) { s += __shfl_xor(s, o); sq += __shfl_xor(sq, o); }
    if ((t & 63) == 0) { rs[t >> 6] = s; rq[t >> 6] = sq; }
    __syncthreads();
    s  = rs[0] + rs[1] + rs[2] + rs[3];
    sq = rq[0] + rq[1] + rq[2] + rq[3];
    float mu  = s * (1.f / D);
    float var = sq * (1.f / D) - mu * mu;
    float inv = rsqrtf(var + EPS_LN);
    const float* gn = g  + n * D;
    const float* bn = bt + n * D;
    op[t]       = f2bf((x0 - mu) * inv * gn[t]       + bn[t]);
    op[t + 256] = f2bf((x1 - mu) * inv * gn[t + 256] + bn[t + 256]);
    op[t + 512] = f2bf((x2 - mu) * inv * gn[t + 512] + bn[t + 512]);
}

// ---------------------------------------------------------------------------
extern "C" void kernel_launch(void* const* d_in, const int* in_sizes, int n_in,
                              void* d_out, int out_size, void* d_ws, size_t ws_size,
                              hipStream_t stream) {
    const float* x    = (const float*)d_in[0];
    const float* phi  = (const float*)d_in[1];
    const float* ln_g = (const float*)d_in[2];
    const float* ln_b = (const float*)d_in[3];
    const float* w1   = (const float*)d_in[4];
    const float* b1   = (const float*)d_in[5];
    const float* w2   = (const float*)d_in[6];
    const float* b2   = (const float*)d_in[7];
    float* out = (float*)d_out;

    char* ws = (char*)d_ws;
    float* logits = (float*)(ws + 0);               // 33.6 MB (reused as Xs fp32)
    u16*   Cb     = (u16*)(ws + 33554432);          // 16.8 MB
    u16*   xb     = (u16*)(ws + 50331648);          // 12.6 MB (xb+DT reused as h1)
    u16*   DT     = (u16*)(ws + 62914560);          // 16.8 MB
    u16*   xTb    = (u16*)(ws + 79691776);          // 12.6 MB (reused as YsT)
    u16*   phinb  = (u16*)(ws + 92274688);          //  1.6 MB
    u16*   hdnE   = (u16*)(ws + 93847552);          // 12.6 MB
    float* pm     = (float*)(ws + 106430464);
    float* pl     = (float*)(ws + 106692608);
    float* fm     = (float*)(ws + 106954752);
    float* fl     = (float*)(ws + 106987520);
    float* Xs     = logits;                         // overlay (logits dead by then)
    u16*   h1     = xb;                             // overlay (xb+DT dead by then)
    u16*   YsT    = xTb;                            // overlay (xTb dead by then)

    // --- operand preparation (single read of x; no weight prep) ---
    xprep_kernel<<<dim3(12, 16, B), 256, 0, stream>>>(x, xb, xTb);
    phi_norm_kernel<<<48, 256, 0, stream>>>(phi, phinb);

    // --- routing ---
    gemm_logits_mfma<<<dim3(8, 64), 256, 0, stream>>>(xb, phinb, logits);
    softmax_row_kernel<<<B * M, 256, 0, stream>>>(logits, Cb);
    colsm_partial_kernel<<<256, 256, 0, stream>>>(logits, pm, pl);
    colsm_combine_kernel<<<32, 256, 0, stream>>>(pm, pl, fm, fl);
    dt_transpose_kernel<<<dim3(16, 16, B), 256, 0, stream>>>(logits, fm, fl, DT);

    // --- dispatch ---
    gemm_dispatch_mfma<<<dim3(6, 8, B), 256, 0, stream>>>(DT, xTb, Xs);
    layernorm_kernel<<<B * S, 256, 0, stream>>>(Xs, ln_g, ln_b, hdnE);

    // --- expert MLP (weights consumed directly from fp32 native layout) ---
    gemm_mlp1_mfma<<<dim3(12, 1, NEXP), 256, 0, stream>>>(hdnE, w1, b1, h1);
    gemm_mlp2_mfma<<<dim3(6, 1, NEXP), 256, 0, stream>>>(h1, w2, b2, YsT);

    // --- combine ---
    gemm_combine_mfma<<<dim3(6, 8, B), 256, 0, stream>>>(Cb, YsT, out);
}